// Round 9
// baseline (217.698 us; speedup 1.0000x reference)
//
#include <hip/hip_runtime.h>

typedef _Float16 f16;
typedef _Float16 f16x8 __attribute__((ext_vector_type(8)));
typedef _Float16 f16x4 __attribute__((ext_vector_type(4)));
typedef float f32x4 __attribute__((ext_vector_type(4)));
typedef float f32x16 __attribute__((ext_vector_type(16)));

#define BATCH 16
#define TLEN 4096
#define SDIM 256
#define MTOT (BATCH * TLEN)        // 65536
#define CHUNK 64                   // scan chunk == M-tile
#define NCHUNK (TLEN / CHUNK)      // 64 per batch
#define NCHTOT (MTOT / CHUNK)      // 1024 total
#define LDK 40                     // padded LDS row stride (halfs)

// ---------------------------------------------------------------------------
// Transpose + fp16 split: Th/Tl[n][k] = split(M[k][n]) for 256x256.
// ---------------------------------------------------------------------------
__global__ __launch_bounds__(256) void tsplit(const float* __restrict__ M,
                                              f16* __restrict__ Th,
                                              f16* __restrict__ Tl) {
    __shared__ float t[64][65];
    const int r0 = blockIdx.x * 64, c0 = blockIdx.y * 64;
    const int cc = threadIdx.x & 63, rr = threadIdx.x >> 6;
#pragma unroll
    for (int i = 0; i < 16; ++i) {
        int r = i * 4 + rr;
        t[r][cc] = M[(size_t)(r0 + r) * 256 + c0 + cc];
    }
    __syncthreads();
#pragma unroll
    for (int i = 0; i < 16; ++i) {
        int n = i * 4 + rr;
        float v = t[cc][n];
        f16 h = (f16)v;
        f16 l = (f16)(v - (float)h);
        Th[(size_t)(c0 + n) * 256 + r0 + cc] = h;
        Tl[(size_t)(c0 + n) * 256 + r0 + cc] = l;
    }
}

// ---------------------------------------------------------------------------
// powA[p][s] = A[s]^(p+1), p = 0..CHUNK-1.
// ---------------------------------------------------------------------------
__global__ __launch_bounds__(256) void powA_kernel(const float* __restrict__ A,
                                                   float* __restrict__ P) {
    const int s = threadIdx.x;
    float a = A[s], pw = 1.f;
    for (int p = 0; p < CHUNK; ++p) {
        pw *= a;
        P[(size_t)p * SDIM + s] = pw;
    }
}

// ---------------------------------------------------------------------------
// K1: Bu-tile GEMM (X@B, fp16-split MFMA, 3 products) fused with chunk-local
// zero-init scan. 256 thr / 4 waves, tile 64 rows x 128 states, BK=32.
// Wave tile 64x32 (acc = 2x16 = 32 regs). Grid: 1024 chunks x 2 state-halves,
// paired as bid and bid+1024 so both halves of a chunk share L2 for X.
// ---------------------------------------------------------------------------
__global__ __launch_bounds__(256, 4) void k1_gemm_scan(
    const float* __restrict__ X, const f16* __restrict__ BhT,
    const f16* __restrict__ BlT, const float* __restrict__ Av,
    float* __restrict__ HL, float* __restrict__ E) {
    __shared__ __align__(16) unsigned char smem[30720];   // staging | hbuf union
    __shared__ float segends[4][64];
    f16 (*Ah)[LDK] = (f16(*)[LDK])(smem);                 // 64*40*2  = 5120
    f16 (*Al)[LDK] = (f16(*)[LDK])(smem + 5120);
    f16 (*Bh)[LDK] = (f16(*)[LDK])(smem + 10240);         // 128*40*2 = 10240
    f16 (*Bl)[LDK] = (f16(*)[LDK])(smem + 20480);
    float (*hbuf)[64] = (float(*)[64])(smem);             // 64*64*4 = 16384

    const int bid = blockIdx.x;
    const int ch = bid & 1023, nh = bid >> 10;
    const int row0 = ch * CHUNK;
    const int n0 = nh * 128;                 // state-half this block owns
    const int tid = threadIdx.x;
    const int w = tid >> 6, lane = tid & 63;
    const int lr = lane & 31, kg8 = (lane >> 5) * 8, lh = lane >> 5;

    f32x16 acc[2] = {};

    for (int ks = 0; ks < 8; ++ks) {
        const int k0 = ks * 32;
        float4 xa[2];
        f16x8 bhv[2], blv[2];
        // A tile: 64x32 fp32 -> 2 float4/thread
#pragma unroll
        for (int i = 0; i < 2; ++i) {
            int f = i * 256 + tid;
            int r = f >> 3, kq = (f & 7) * 4;
            xa[i] = *reinterpret_cast<const float4*>(
                &X[(size_t)(row0 + r) * SDIM + k0 + kq]);
        }
        // B tile: 128x32 hi/lo -> 2 f16x8 each/thread
#pragma unroll
        for (int i = 0; i < 2; ++i) {
            int f = i * 256 + tid;
            int r = f >> 2, ko = (f & 3) * 8;
            bhv[i] = *reinterpret_cast<const f16x8*>(
                &BhT[(size_t)(n0 + r) * SDIM + k0 + ko]);
            blv[i] = *reinterpret_cast<const f16x8*>(
                &BlT[(size_t)(n0 + r) * SDIM + k0 + ko]);
        }
        __syncthreads();   // previous MFMA done before LDS overwrite
#pragma unroll
        for (int i = 0; i < 2; ++i) {
            int f = i * 256 + tid;
            int r = f >> 3, kq = (f & 7) * 4;
            const float* xs = reinterpret_cast<const float*>(&xa[i]);
            f16x4 hv, lv;
#pragma unroll
            for (int c = 0; c < 4; ++c) {
                float x = xs[c];
                f16 h = (f16)x;
                hv[c] = h;
                lv[c] = (f16)(x - (float)h);
            }
            *reinterpret_cast<f16x4*>(&Ah[r][kq]) = hv;
            *reinterpret_cast<f16x4*>(&Al[r][kq]) = lv;
        }
#pragma unroll
        for (int i = 0; i < 2; ++i) {
            int f = i * 256 + tid;
            int r = f >> 2, ko = (f & 3) * 8;
            *reinterpret_cast<f16x8*>(&Bh[r][ko]) = bhv[i];
            *reinterpret_cast<f16x8*>(&Bl[r][ko]) = blv[i];
        }
        __syncthreads();
#pragma unroll
        for (int sl = 0; sl < 2; ++sl) {
            const int ko = sl * 16 + kg8;
            f16x8 a_h[2], a_l[2], b_h, b_l;
#pragma unroll
            for (int q = 0; q < 2; ++q) {
                a_h[q] = *reinterpret_cast<const f16x8*>(&Ah[q * 32 + lr][ko]);
                a_l[q] = *reinterpret_cast<const f16x8*>(&Al[q * 32 + lr][ko]);
            }
            b_h = *reinterpret_cast<const f16x8*>(&Bh[w * 32 + lr][ko]);
            b_l = *reinterpret_cast<const f16x8*>(&Bl[w * 32 + lr][ko]);
#pragma unroll
            for (int i = 0; i < 2; ++i) {
                acc[i] = __builtin_amdgcn_mfma_f32_32x32x16_f16(a_h[i], b_h, acc[i], 0, 0, 0);
                acc[i] = __builtin_amdgcn_mfma_f32_32x32x16_f16(a_h[i], b_l, acc[i], 0, 0, 0);
                acc[i] = __builtin_amdgcn_mfma_f32_32x32x16_f16(a_l[i], b_h, acc[i], 0, 0, 0);
            }
        }
    }

    // ---- fused chunk-local scan epilogue: two 64-col passes over hbuf
    const int c = tid & 63;
    const int seg = tid >> 6;            // 0..3 row segments of 16
#pragma unroll
    for (int p = 0; p < 2; ++p) {
        __syncthreads();                 // staging / previous-pass readers done
        if ((w >> 1) == p) {             // wave-cols 2p,2p+1 own these 64 cols
#pragma unroll
            for (int i = 0; i < 2; ++i)
#pragma unroll
                for (int g = 0; g < 16; ++g) {
                    int row = i * 32 + (g & 3) + 8 * (g >> 2) + 4 * lh;
                    hbuf[row][(w & 1) * 32 + lr] = acc[i][g];
                }
        }
        __syncthreads();
        const float a = Av[n0 + p * 64 + c];
        float sv[16];
        float h = 0.f;
#pragma unroll
        for (int r = 0; r < 16; ++r) {
            h = fmaf(h, a, hbuf[seg * 16 + r][c]);
            sv[r] = h;
        }
        segends[seg][c] = h;
        __syncthreads();
        float a16 = a;
#pragma unroll
        for (int i = 0; i < 4; ++i) a16 *= a16;   // a^16
        const float a32 = a16 * a16;
        float carry = 0.f;
        if (seg >= 1) carry = segends[seg - 1][c];
        if (seg >= 2) carry = fmaf(a16, segends[seg - 2][c], carry);
        if (seg >= 3) carry = fmaf(a32, segends[seg - 3][c], carry);
        float pw = a;
#pragma unroll
        for (int r = 0; r < 16; ++r) {
            float hc = fmaf(pw, carry, sv[r]);
            pw *= a;
            HL[(size_t)(row0 + seg * 16 + r) * SDIM + n0 + p * 64 + c] = hc;
            if (seg == 3 && r == 15)
                E[(size_t)ch * SDIM + n0 + p * 64 + c] = hc;   // chunk end
        }
    }
}

// ---------------------------------------------------------------------------
// K3: Y-tile GEMM ((h_local + A^{p+1} o H_in) @ C). Carry H_in computed in a
// per-block prologue from E (L2-hot) — no separate carries kernel, no H array.
// Same 64x128 tile geometry as K1.
// ---------------------------------------------------------------------------
__global__ __launch_bounds__(256, 4) void k3_gemm_out(
    const float* __restrict__ HL, const f16* __restrict__ ChT,
    const f16* __restrict__ ClT, const float* __restrict__ PW,
    const float* __restrict__ E, const float* __restrict__ Av,
    const float* __restrict__ h0, float* __restrict__ Y) {
    __shared__ __align__(16) f16 Ah[64][LDK], Al[64][LDK];
    __shared__ __align__(16) f16 Bh[128][LDK], Bl[128][LDK];
    __shared__ float Hin[256];

    const int bid = blockIdx.x;
    const int ch = bid & 1023, nh = bid >> 10;
    const int row0 = ch * CHUNK;
    const int n0 = nh * 128;                 // output-col half
    const int tid = threadIdx.x;
    const int w = tid >> 6, lane = tid & 63;
    const int lr = lane & 31, kg8 = (lane >> 5) * 8, lh = lane >> 5;

    // ---- prologue: state entering chunk ch (redundant per block, E is L2-hot)
    {
        const int s = tid;                   // 256 threads == 256 states
        const int b = ch >> 6, kb = ch & 63;
        float a = Av[s], aL = a;
#pragma unroll
        for (int i = 0; i < 6; ++i) aL *= aL;   // a^64
        float h = h0[s];
        for (int j = 0; j < kb; ++j)
            h = fmaf(h, aL, E[(size_t)(b * 64 + j) * SDIM + s]);
        Hin[s] = h;
    }
    __syncthreads();

    f32x16 acc[2] = {};

    for (int ks = 0; ks < 8; ++ks) {
        const int k0 = ks * 32;
        f32x4 xa[2];
        f16x8 bhv[2], blv[2];
#pragma unroll
        for (int i = 0; i < 2; ++i) {
            int f = i * 256 + tid;
            int r = f >> 3, kq = (f & 7) * 4;
            f32x4 hv = *reinterpret_cast<const f32x4*>(
                &HL[(size_t)(row0 + r) * SDIM + k0 + kq]);
            f32x4 pw = *reinterpret_cast<const f32x4*>(&PW[(size_t)r * SDIM + k0 + kq]);
            f32x4 hc = *reinterpret_cast<const f32x4*>(&Hin[k0 + kq]);
            xa[i] = hv + pw * hc;            // h_t = h_local + a^{p+1} * H_in
        }
#pragma unroll
        for (int i = 0; i < 2; ++i) {
            int f = i * 256 + tid;
            int r = f >> 2, ko = (f & 3) * 8;
            bhv[i] = *reinterpret_cast<const f16x8*>(
                &ChT[(size_t)(n0 + r) * SDIM + k0 + ko]);
            blv[i] = *reinterpret_cast<const f16x8*>(
                &ClT[(size_t)(n0 + r) * SDIM + k0 + ko]);
        }
        __syncthreads();
#pragma unroll
        for (int i = 0; i < 2; ++i) {
            int f = i * 256 + tid;
            int r = f >> 3, kq = (f & 7) * 4;
            f16x4 hv, lv;
#pragma unroll
            for (int c = 0; c < 4; ++c) {
                float x = xa[i][c];
                f16 h = (f16)x;
                hv[c] = h;
                lv[c] = (f16)(x - (float)h);
            }
            *reinterpret_cast<f16x4*>(&Ah[r][kq]) = hv;
            *reinterpret_cast<f16x4*>(&Al[r][kq]) = lv;
        }
#pragma unroll
        for (int i = 0; i < 2; ++i) {
            int f = i * 256 + tid;
            int r = f >> 2, ko = (f & 3) * 8;
            *reinterpret_cast<f16x8*>(&Bh[r][ko]) = bhv[i];
            *reinterpret_cast<f16x8*>(&Bl[r][ko]) = blv[i];
        }
        __syncthreads();
#pragma unroll
        for (int sl = 0; sl < 2; ++sl) {
            const int ko = sl * 16 + kg8;
            f16x8 a_h[2], a_l[2], b_h, b_l;
#pragma unroll
            for (int q = 0; q < 2; ++q) {
                a_h[q] = *reinterpret_cast<const f16x8*>(&Ah[q * 32 + lr][ko]);
                a_l[q] = *reinterpret_cast<const f16x8*>(&Al[q * 32 + lr][ko]);
            }
            b_h = *reinterpret_cast<const f16x8*>(&Bh[w * 32 + lr][ko]);
            b_l = *reinterpret_cast<const f16x8*>(&Bl[w * 32 + lr][ko]);
#pragma unroll
            for (int i = 0; i < 2; ++i) {
                acc[i] = __builtin_amdgcn_mfma_f32_32x32x16_f16(a_h[i], b_h, acc[i], 0, 0, 0);
                acc[i] = __builtin_amdgcn_mfma_f32_32x32x16_f16(a_h[i], b_l, acc[i], 0, 0, 0);
                acc[i] = __builtin_amdgcn_mfma_f32_32x32x16_f16(a_l[i], b_h, acc[i], 0, 0, 0);
            }
        }
    }

#pragma unroll
    for (int i = 0; i < 2; ++i)
#pragma unroll
        for (int g = 0; g < 16; ++g) {
            int row = row0 + i * 32 + (g & 3) + 8 * (g >> 2) + 4 * lh;
            int col = n0 + w * 32 + lr;
            Y[(size_t)row * SDIM + col] = acc[i][g];
        }
}

// ---------------------------------------------------------------------------
extern "C" void kernel_launch(void* const* d_in, const int* in_sizes, int n_in,
                              void* d_out, int out_size, void* d_ws, size_t ws_size,
                              hipStream_t stream) {
    const float* X  = (const float*)d_in[0];
    const float* Av = (const float*)d_in[1];
    const float* Bm = (const float*)d_in[2];
    const float* Cm = (const float*)d_in[3];
    const float* h0 = (const float*)d_in[4];
    float* Y = (float*)d_out;

    // ws layout: HL (67MB) | BhT BlT ChT ClT (4x128KB) | PW (64KB) | E (1MB)
    char* w = (char*)d_ws;
    float* HL = (float*)w;                       w += (size_t)MTOT * SDIM * 4;
    f16* BhT = (f16*)w;                          w += 256 * 256 * 2;
    f16* BlT = (f16*)w;                          w += 256 * 256 * 2;
    f16* ChT = (f16*)w;                          w += 256 * 256 * 2;
    f16* ClT = (f16*)w;                          w += 256 * 256 * 2;
    float* PW = (float*)w;                       w += CHUNK * SDIM * 4;
    float* E  = (float*)w;

    tsplit<<<dim3(4, 4), 256, 0, stream>>>(Bm, BhT, BlT);
    tsplit<<<dim3(4, 4), 256, 0, stream>>>(Cm, ChT, ClT);
    powA_kernel<<<1, 256, 0, stream>>>(Av, PW);

    k1_gemm_scan<<<2 * NCHTOT, 256, 0, stream>>>(X, BhT, BlT, Av, HL, E);
    k3_gemm_out<<<2 * NCHTOT, 256, 0, stream>>>(HL, ChT, ClT, PW, E, Av, h0, Y);
}

// Round 10
// 203.063 us; speedup vs baseline: 1.0721x; 1.0721x over previous
//
#include <hip/hip_runtime.h>

typedef _Float16 f16;
typedef _Float16 f16x8 __attribute__((ext_vector_type(8)));
typedef _Float16 f16x4 __attribute__((ext_vector_type(4)));
typedef float f32x4 __attribute__((ext_vector_type(4)));
typedef float f32x16 __attribute__((ext_vector_type(16)));

#define BATCH 16
#define TLEN 4096
#define SDIM 256
#define MTOT (BATCH * TLEN)        // 65536
#define CHUNK 128                  // scan chunk == M-tile
#define NCHUNK (TLEN / CHUNK)      // 32 per batch
#define NCHTOT (MTOT / CHUNK)      // 512 total
#define LDK 40                     // padded LDS row stride (halfs)

// ---------------------------------------------------------------------------
// Transpose + fp16 split: Th/Tl[n][k] = split(M[k][n]) for 256x256.
// ---------------------------------------------------------------------------
__global__ __launch_bounds__(256) void tsplit(const float* __restrict__ M,
                                              f16* __restrict__ Th,
                                              f16* __restrict__ Tl) {
    __shared__ float t[64][65];
    const int r0 = blockIdx.x * 64, c0 = blockIdx.y * 64;
    const int cc = threadIdx.x & 63, rr = threadIdx.x >> 6;
#pragma unroll
    for (int i = 0; i < 16; ++i) {
        int r = i * 4 + rr;
        t[r][cc] = M[(size_t)(r0 + r) * 256 + c0 + cc];
    }
    __syncthreads();
#pragma unroll
    for (int i = 0; i < 16; ++i) {
        int n = i * 4 + rr;
        float v = t[cc][n];
        f16 h = (f16)v;
        f16 l = (f16)(v - (float)h);
        Th[(size_t)(c0 + n) * 256 + r0 + cc] = h;
        Tl[(size_t)(c0 + n) * 256 + r0 + cc] = l;
    }
}

// ---------------------------------------------------------------------------
// powA[p][s] = A[s]^(p+1), p = 0..CHUNK-1.
// ---------------------------------------------------------------------------
__global__ __launch_bounds__(256) void powA_kernel(const float* __restrict__ A,
                                                   float* __restrict__ P) {
    const int s = threadIdx.x;
    float a = A[s], pw = 1.f;
    for (int p = 0; p < CHUNK; ++p) {
        pw *= a;
        P[(size_t)p * SDIM + s] = pw;
    }
}

// ---------------------------------------------------------------------------
// K1: Bu-tile GEMM (X@B, fp16-split MFMA) fused with chunk-local scan.
// 512 thr / 8 waves, BM=128, BN=256, BK=32, register prefetch of K-step t+1
// issued before the MFMA section of step t (hides HBM latency under MFMA).
// ---------------------------------------------------------------------------
__global__ __launch_bounds__(512, 2) void k1_gemm_scan(
    const float* __restrict__ X, const f16* __restrict__ BhT,
    const f16* __restrict__ BlT, const float* __restrict__ Av,
    float* __restrict__ HL, float* __restrict__ E) {
    __shared__ __align__(16) unsigned char smem[65536];   // staging | hbuf union
    __shared__ float segends[4][128];
    f16 (*Ah)[LDK] = (f16(*)[LDK])(smem);                 // 128*40*2 = 10240
    f16 (*Al)[LDK] = (f16(*)[LDK])(smem + 10240);
    f16 (*Bh)[LDK] = (f16(*)[LDK])(smem + 20480);         // 256*40*2 = 20480
    f16 (*Bl)[LDK] = (f16(*)[LDK])(smem + 40960);
    float (*hbuf)[128] = (float(*)[128])(smem);           // 128*128*4 = 64KB

    const int ch = blockIdx.x;          // global chunk 0..511
    const int row0 = ch * CHUNK;
    const int tid = threadIdx.x;
    const int wid = tid >> 6, lane = tid & 63;
    const int wm = (wid & 1) * 64, wn = (wid >> 1) * 64;
    const int lr = lane & 31, kg8 = (lane >> 5) * 8, lh = lane >> 5;

    f32x16 acc[2][2] = {};

    float4 xa[2];
    f16x8 pbh[2], pbl[2];

    auto load_g = [&](int k0) {
#pragma unroll
        for (int i = 0; i < 2; ++i) {
            int f = i * 512 + tid;
            int r = f >> 3, kq = (f & 7) * 4;
            xa[i] = *reinterpret_cast<const float4*>(
                &X[(size_t)(row0 + r) * SDIM + k0 + kq]);
        }
#pragma unroll
        for (int i = 0; i < 2; ++i) {
            int f = i * 512 + tid;
            int r = f >> 2, ko = (f & 3) * 8;
            pbh[i] = *reinterpret_cast<const f16x8*>(&BhT[(size_t)r * SDIM + k0 + ko]);
            pbl[i] = *reinterpret_cast<const f16x8*>(&BlT[(size_t)r * SDIM + k0 + ko]);
        }
    };

    load_g(0);

    for (int ks = 0; ks < 8; ++ks) {
        __syncthreads();   // previous MFMA done before LDS overwrite
#pragma unroll
        for (int i = 0; i < 2; ++i) {
            int f = i * 512 + tid;
            int r = f >> 3, kq = (f & 7) * 4;
            const float* xs = reinterpret_cast<const float*>(&xa[i]);
            f16x4 hv, lv;
#pragma unroll
            for (int c = 0; c < 4; ++c) {
                float x = xs[c];
                f16 h = (f16)x;
                hv[c] = h;
                lv[c] = (f16)(x - (float)h);
            }
            *reinterpret_cast<f16x4*>(&Ah[r][kq]) = hv;
            *reinterpret_cast<f16x4*>(&Al[r][kq]) = lv;
        }
#pragma unroll
        for (int i = 0; i < 2; ++i) {
            int f = i * 512 + tid;
            int r = f >> 2, ko = (f & 3) * 8;
            *reinterpret_cast<f16x8*>(&Bh[r][ko]) = pbh[i];
            *reinterpret_cast<f16x8*>(&Bl[r][ko]) = pbl[i];
        }
        __syncthreads();

        if (ks < 7) load_g((ks + 1) * 32);   // prefetch overlaps MFMA below

#pragma unroll
        for (int sl = 0; sl < 2; ++sl) {
            const int ko = sl * 16 + kg8;
            f16x8 a_h[2], a_l[2], b_h[2], b_l[2];
#pragma unroll
            for (int q = 0; q < 2; ++q) {
                a_h[q] = *reinterpret_cast<const f16x8*>(&Ah[wm + q * 32 + lr][ko]);
                a_l[q] = *reinterpret_cast<const f16x8*>(&Al[wm + q * 32 + lr][ko]);
                b_h[q] = *reinterpret_cast<const f16x8*>(&Bh[wn + q * 32 + lr][ko]);
                b_l[q] = *reinterpret_cast<const f16x8*>(&Bl[wn + q * 32 + lr][ko]);
            }
#pragma unroll
            for (int i = 0; i < 2; ++i)
#pragma unroll
                for (int j = 0; j < 2; ++j) {
                    acc[i][j] = __builtin_amdgcn_mfma_f32_32x32x16_f16(
                        a_h[i], b_h[j], acc[i][j], 0, 0, 0);
                    acc[i][j] = __builtin_amdgcn_mfma_f32_32x32x16_f16(
                        a_h[i], b_l[j], acc[i][j], 0, 0, 0);
                    acc[i][j] = __builtin_amdgcn_mfma_f32_32x32x16_f16(
                        a_l[i], b_h[j], acc[i][j], 0, 0, 0);
                }
        }
    }

    // ---- fused chunk-local scan epilogue, two 128-col halves (R6-verified)
    const int c = tid & 127;
    const int seg = tid >> 7;           // 0..3 row segments of 32
#pragma unroll
    for (int half = 0; half < 2; ++half) {
        __syncthreads();                // MFMA / previous-half readers done
        if ((wid >> 2) == half) {       // waves 0-3 own cols 0-127; 4-7 own 128-255
#pragma unroll
            for (int i = 0; i < 2; ++i)
#pragma unroll
                for (int j = 0; j < 2; ++j)
#pragma unroll
                    for (int g = 0; g < 16; ++g) {
                        int row = wm + i * 32 + (g & 3) + 8 * (g >> 2) + 4 * lh;
                        hbuf[row][(wn & 127) + j * 32 + lr] = acc[i][j][g];
                    }
        }
        __syncthreads();
        const float a = Av[half * 128 + c];
        float sv[32];
        float h = 0.f;
#pragma unroll
        for (int r = 0; r < 32; ++r) {
            h = fmaf(h, a, hbuf[seg * 32 + r][c]);
            sv[r] = h;
        }
        segends[seg][c] = h;
        __syncthreads();
        float a32 = a;
#pragma unroll
        for (int i = 0; i < 5; ++i) a32 *= a32;   // a^32
        const float a64 = a32 * a32;
        float carry = 0.f;
        if (seg >= 1) carry = segends[seg - 1][c];
        if (seg >= 2) carry = fmaf(a32, segends[seg - 2][c], carry);
        if (seg >= 3) carry = fmaf(a64, segends[seg - 3][c], carry);
        float pw = a;
#pragma unroll
        for (int r = 0; r < 32; ++r) {
            float hc = fmaf(pw, carry, sv[r]);
            pw *= a;
            HL[(size_t)(row0 + seg * 32 + r) * SDIM + half * 128 + c] = hc;
            if (seg == 3 && r == 31)
                E[(size_t)ch * SDIM + half * 128 + c] = hc;   // chunk end
        }
    }
}

// ---------------------------------------------------------------------------
// K3: Y-tile GEMM ((h_local + A^{p+1} o H_in) @ C). H_in carry computed in a
// per-block prologue from E (L2-hot, <=31 fmaf chain). Register prefetch as k1.
// ---------------------------------------------------------------------------
__global__ __launch_bounds__(512, 2) void k3_gemm_out(
    const float* __restrict__ HL, const f16* __restrict__ ChT,
    const f16* __restrict__ ClT, const float* __restrict__ PW,
    const float* __restrict__ E, const float* __restrict__ Av,
    const float* __restrict__ h0, float* __restrict__ Y) {
    __shared__ __align__(16) f16 Ah[128][LDK], Al[128][LDK];
    __shared__ __align__(16) f16 Bh[256][LDK], Bl[256][LDK];
    __shared__ float Hin[256];

    const int ch = blockIdx.x;
    const int row0 = ch * CHUNK;
    const int tid = threadIdx.x;
    const int wid = tid >> 6, lane = tid & 63;
    const int wm = (wid & 1) * 64, wn = (wid >> 1) * 64;
    const int lr = lane & 31, kg8 = (lane >> 5) * 8, lh = lane >> 5;

    // ---- prologue: state entering chunk ch (redundant per block, E L2-hot)
    if (tid < 256) {
        const int s = tid;
        const int b = ch >> 5, kb = ch & 31;
        float a = Av[s], aL = a;
#pragma unroll
        for (int i = 0; i < 7; ++i) aL *= aL;   // a^128
        float h = h0[s];
        for (int j = 0; j < kb; ++j)
            h = fmaf(h, aL, E[(size_t)(b * 32 + j) * SDIM + s]);
        Hin[s] = h;
    }
    __syncthreads();

    f32x16 acc[2][2] = {};

    f32x4 xa[2];
    f16x8 pbh[2], pbl[2];

    auto load_g = [&](int k0) {
#pragma unroll
        for (int i = 0; i < 2; ++i) {
            int f = i * 512 + tid;
            int r = f >> 3, kq = (f & 7) * 4;
            f32x4 hv = *reinterpret_cast<const f32x4*>(
                &HL[(size_t)(row0 + r) * SDIM + k0 + kq]);
            f32x4 pw = *reinterpret_cast<const f32x4*>(&PW[(size_t)r * SDIM + k0 + kq]);
            f32x4 hc = *reinterpret_cast<const f32x4*>(&Hin[k0 + kq]);
            xa[i] = hv + pw * hc;            // h_t = h_local + a^{p+1} * H_in
        }
#pragma unroll
        for (int i = 0; i < 2; ++i) {
            int f = i * 512 + tid;
            int r = f >> 2, ko = (f & 3) * 8;
            pbh[i] = *reinterpret_cast<const f16x8*>(&ChT[(size_t)r * SDIM + k0 + ko]);
            pbl[i] = *reinterpret_cast<const f16x8*>(&ClT[(size_t)r * SDIM + k0 + ko]);
        }
    };

    load_g(0);

    for (int ks = 0; ks < 8; ++ks) {
        __syncthreads();
#pragma unroll
        for (int i = 0; i < 2; ++i) {
            int f = i * 512 + tid;
            int r = f >> 3, kq = (f & 7) * 4;
            f16x4 hv, lv;
#pragma unroll
            for (int c = 0; c < 4; ++c) {
                float x = xa[i][c];
                f16 h = (f16)x;
                hv[c] = h;
                lv[c] = (f16)(x - (float)h);
            }
            *reinterpret_cast<f16x4*>(&Ah[r][kq]) = hv;
            *reinterpret_cast<f16x4*>(&Al[r][kq]) = lv;
        }
#pragma unroll
        for (int i = 0; i < 2; ++i) {
            int f = i * 512 + tid;
            int r = f >> 2, ko = (f & 3) * 8;
            *reinterpret_cast<f16x8*>(&Bh[r][ko]) = pbh[i];
            *reinterpret_cast<f16x8*>(&Bl[r][ko]) = pbl[i];
        }
        __syncthreads();

        if (ks < 7) load_g((ks + 1) * 32);   // prefetch overlaps MFMA below

#pragma unroll
        for (int sl = 0; sl < 2; ++sl) {
            const int ko = sl * 16 + kg8;
            f16x8 a_h[2], a_l[2], b_h[2], b_l[2];
#pragma unroll
            for (int q = 0; q < 2; ++q) {
                a_h[q] = *reinterpret_cast<const f16x8*>(&Ah[wm + q * 32 + lr][ko]);
                a_l[q] = *reinterpret_cast<const f16x8*>(&Al[wm + q * 32 + lr][ko]);
                b_h[q] = *reinterpret_cast<const f16x8*>(&Bh[wn + q * 32 + lr][ko]);
                b_l[q] = *reinterpret_cast<const f16x8*>(&Bl[wn + q * 32 + lr][ko]);
            }
#pragma unroll
            for (int i = 0; i < 2; ++i)
#pragma unroll
                for (int j = 0; j < 2; ++j) {
                    acc[i][j] = __builtin_amdgcn_mfma_f32_32x32x16_f16(
                        a_h[i], b_h[j], acc[i][j], 0, 0, 0);
                    acc[i][j] = __builtin_amdgcn_mfma_f32_32x32x16_f16(
                        a_h[i], b_l[j], acc[i][j], 0, 0, 0);
                    acc[i][j] = __builtin_amdgcn_mfma_f32_32x32x16_f16(
                        a_l[i], b_h[j], acc[i][j], 0, 0, 0);
                }
        }
    }

#pragma unroll
    for (int i = 0; i < 2; ++i)
#pragma unroll
        for (int j = 0; j < 2; ++j)
#pragma unroll
            for (int g = 0; g < 16; ++g) {
                int row = row0 + wm + i * 32 + (g & 3) + 8 * (g >> 2) + 4 * lh;
                int col = wn + j * 32 + lr;
                Y[(size_t)row * SDIM + col] = acc[i][j][g];
            }
}

// ---------------------------------------------------------------------------
extern "C" void kernel_launch(void* const* d_in, const int* in_sizes, int n_in,
                              void* d_out, int out_size, void* d_ws, size_t ws_size,
                              hipStream_t stream) {
    const float* X  = (const float*)d_in[0];
    const float* Av = (const float*)d_in[1];
    const float* Bm = (const float*)d_in[2];
    const float* Cm = (const float*)d_in[3];
    const float* h0 = (const float*)d_in[4];
    float* Y = (float*)d_out;

    // ws layout: HL (67MB) | BhT BlT ChT ClT (4x128KB) | PW (128KB) | E (512KB)
    char* w = (char*)d_ws;
    float* HL = (float*)w;                       w += (size_t)MTOT * SDIM * 4;
    f16* BhT = (f16*)w;                          w += 256 * 256 * 2;
    f16* BlT = (f16*)w;                          w += 256 * 256 * 2;
    f16* ChT = (f16*)w;                          w += 256 * 256 * 2;
    f16* ClT = (f16*)w;                          w += 256 * 256 * 2;
    float* PW = (float*)w;                       w += CHUNK * SDIM * 4;
    float* E  = (float*)w;

    tsplit<<<dim3(4, 4), 256, 0, stream>>>(Bm, BhT, BlT);
    tsplit<<<dim3(4, 4), 256, 0, stream>>>(Cm, ChT, ClT);
    powA_kernel<<<1, 256, 0, stream>>>(Av, PW);

    k1_gemm_scan<<<NCHTOT, 512, 0, stream>>>(X, BhT, BlT, Av, HL, E);
    k3_gemm_out<<<NCHTOT, 512, 0, stream>>>(HL, ChT, ClT, PW, E, Av, h0, Y);
}